// Round 12
// baseline (828.895 us; speedup 1.0000x reference)
//
#include <hip/hip_runtime.h>

#define D 128
#define NG 64
#define NC 16
#define NEG 0.1f

typedef __attribute__((ext_vector_type(8))) short bf16x8;
typedef __attribute__((ext_vector_type(4))) float f32x4;

// ---------- bf16 <-> fp32 helpers (bf16 stored as ushort, packed pairs in uint) ----------
__device__ __forceinline__ float bf2f(unsigned int u16) {
    union { unsigned int i; float f; } c;
    c.i = u16 << 16;
    return c.f;
}
__device__ __forceinline__ unsigned short f2bf(float f) {
    union { float f; unsigned int i; } c;
    c.f = f;
    unsigned int i = c.i;
    unsigned int r = (i + 0x7FFFu + ((i >> 16) & 1u)) >> 16;  // RNE
    return (unsigned short)r;
}

// ---------------- fused prep ----------------
// blocks 0..15: W1/W2 -> bf16 fragment-order image; 16..47: zero pooled; 48+: degree histogram.
__global__ void prep_misc_kernel(const float* __restrict__ W1, unsigned short* __restrict__ Wf1,
                                 const float* __restrict__ W2, unsigned short* __restrict__ Wf2,
                                 float* __restrict__ pooled,
                                 const int* __restrict__ dst, int* __restrict__ deg, int E) {
    int b = blockIdx.x;
    if (b < 16) {
        const float* W = (b < 8) ? W1 : W2;
        unsigned short* Wf = (b < 8) ? Wf1 : Wf2;
        int fid = (b & 7) * 256 + threadIdx.x;  // 0..2047 fragment entries
        int m = fid & 15;
        int quad = (fid >> 4) & 3;
        int kc = (fid >> 6) & 3;
        int t = fid >> 8;
        int n = t * 16 + m;
        int k0 = kc * 32 + quad * 8;
        unsigned short r[8];
#pragma unroll
        for (int j = 0; j < 8; j++) r[j] = f2bf(W[(k0 + j) * 128 + n]);
        uint4 v;
        v.x = (unsigned int)r[0] | ((unsigned int)r[1] << 16);
        v.y = (unsigned int)r[2] | ((unsigned int)r[3] << 16);
        v.z = (unsigned int)r[4] | ((unsigned int)r[5] << 16);
        v.w = (unsigned int)r[6] | ((unsigned int)r[7] << 16);
        ((uint4*)Wf)[fid] = v;
    } else if (b < 48) {
        pooled[(b - 16) * 256 + threadIdx.x] = 0.f;
    } else {
        int e = (b - 48) * 256 + threadIdx.x;
        if (e < E) atomicAdd(&deg[dst[e]], 1);
    }
}

// ---------------- scan stage 1 (+ dinv fold) ----------------
__global__ void scan_block_kernel(const int* __restrict__ deg, int* __restrict__ scan1,
                                  int* __restrict__ blocksum, float* __restrict__ dinv, int N) {
    __shared__ int sm[256];
    int tid = threadIdx.x;
    int i = blockIdx.x * 256 + tid;
    int v = (i < N) ? deg[i] : 0;
    if (i < N) dinv[i] = 1.0f / sqrtf((float)v + 1.0f);
    sm[tid] = v;
    __syncthreads();
    for (int off = 1; off < 256; off <<= 1) {
        int t = (tid >= off) ? sm[tid - off] : 0;
        __syncthreads();
        sm[tid] += t;
        __syncthreads();
    }
    if (i < N) scan1[i] = sm[tid];  // inclusive
    if (tid == 255) blocksum[blockIdx.x] = sm[255];
}

// ---------------- finalize: ptr = exclusive prefix; each block re-scans blocksum in LDS ----------
__global__ void finalize_ptr_kernel(const int* __restrict__ deg, const int* __restrict__ scan1,
                                    const int* __restrict__ blocksum, int* __restrict__ ptr,
                                    int* __restrict__ fill, int nb, int N, int E) {
    __shared__ int sm[256];
    int tid = threadIdx.x;
    int v = (tid < nb) ? blocksum[tid] : 0;
    sm[tid] = v;
    __syncthreads();
    for (int off = 1; off < 256; off <<= 1) {
        int t = (tid >= off) ? sm[tid - off] : 0;
        __syncthreads();
        sm[tid] += t;
        __syncthreads();
    }
    int blockoff = (blockIdx.x > 0) ? sm[blockIdx.x - 1] : 0;  // exclusive prefix for this block
    int i = blockIdx.x * 256 + tid;
    if (i < N) {
        ptr[i] = scan1[i] - deg[i] + blockoff;
        fill[i] = 0;
        if (i == N - 1) ptr[N] = E;
    }
}

// ---------------- scatter edges into CSR by dst; packed (src, coef) int2 ----------------
__global__ void scatter_kernel(const int* __restrict__ src, const int* __restrict__ dst,
                               const int* __restrict__ ptr, int* __restrict__ fill,
                               const float* __restrict__ dinv,
                               int2* __restrict__ csr_edge, int E) {
    int e = blockIdx.x * blockDim.x + threadIdx.x;
    if (e < E) {
        int d = dst[e];
        int s = src[e];
        int pos = ptr[d] + atomicAdd(&fill[d], 1);
        float coef = dinv[s] * dinv[d];
        csr_edge[pos] = make_int2(s, __float_as_int(coef));
    }
}

// ---------------- MFMA GEMM: C[N,128](packed bf16) = A[N,128] @ W ----------------
template <bool AF32>
__global__ __launch_bounds__(256) void gemm_mfma_kernel(const void* __restrict__ Ap,
                                                        const uint4* __restrict__ Wf,
                                                        unsigned int* __restrict__ C, int N) {
    __shared__ uint4 Ws[2048];  // 32 KB, fragment-order image
    int tid = threadIdx.x;
    int w = tid >> 6, lane = tid & 63;
    int quad = lane >> 4, m = lane & 15;
    int rowstart = blockIdx.x * 64;

    // stage W image (contiguous copy)
#pragma unroll
    for (int i = 0; i < 8; i++) Ws[tid + 256 * i] = Wf[tid + 256 * i];

    // A fragments from global: row 16w+m, k = kc*32 + quad*8 + j
    int arow = rowstart + 16 * w + m;
    bool valid = arow < N;
    bf16x8 af[4];
    if (AF32) {
        const float* Ag = (const float*)Ap;
#pragma unroll
        for (int kc = 0; kc < 4; kc++) {
            float4 f0 = make_float4(0.f, 0.f, 0.f, 0.f), f1 = f0;
            if (valid) {
                const float4* p = (const float4*)(Ag + (size_t)arow * 128 + kc * 32 + quad * 8);
                f0 = p[0];
                f1 = p[1];
            }
            bf16x8 a;
            a[0] = (short)f2bf(f0.x); a[1] = (short)f2bf(f0.y);
            a[2] = (short)f2bf(f0.z); a[3] = (short)f2bf(f0.w);
            a[4] = (short)f2bf(f1.x); a[5] = (short)f2bf(f1.y);
            a[6] = (short)f2bf(f1.z); a[7] = (short)f2bf(f1.w);
            af[kc] = a;
        }
    } else {
        const unsigned short* Ag = (const unsigned short*)Ap;
#pragma unroll
        for (int kc = 0; kc < 4; kc++) {
            bf16x8 a;
#pragma unroll
            for (int j = 0; j < 8; j++) a[j] = 0;
            if (valid) a = *(const bf16x8*)(Ag + (size_t)arow * 128 + kc * 32 + quad * 8);
            af[kc] = a;
        }
    }
    __syncthreads();

    f32x4 acc[8];
#pragma unroll
    for (int t = 0; t < 8; t++) acc[t] = (f32x4){0.f, 0.f, 0.f, 0.f};

#pragma unroll
    for (int t = 0; t < 8; t++) {
#pragma unroll
        for (int kc = 0; kc < 4; kc++) {
            bf16x8 bh = *(const bf16x8*)&Ws[(((t * 4 + kc) * 4 + quad) * 16 + m)];
            acc[t] = __builtin_amdgcn_mfma_f32_16x16x32_bf16(af[kc], bh, acc[t], 0, 0, 0);
        }
    }

    // epilogue: C[row = 16w + quad*4 + r][col = t*16 + m]; pack pairs across m via shfl_xor(1)
#pragma unroll
    for (int t = 0; t < 8; t++) {
#pragma unroll
        for (int r = 0; r < 4; r++) {
            int row = rowstart + 16 * w + quad * 4 + r;
            unsigned int us = f2bf(acc[t][r]);
            unsigned int other = (unsigned int)__shfl_xor((int)us, 1);
            if (((m & 1) == 0) && row < N)
                C[(size_t)row * 64 + t * 8 + (m >> 1)] = us | (other << 16);
        }
    }
}

// ---------------- gather + self-loop + bias + leaky_relu (+ optional fused mean-pool) ----------
// one wave per node; 16 lanes/row (uint4 = 8 feats), 4 rows in flight, 2x unroll.
// POOL=true: instead of storing the row, atomically accumulate fp32 into pooled[batch[i]*D+f].
template <bool POOL>
__global__ void combine_kernel(const uint4* __restrict__ h4, const int* __restrict__ ptr,
                               const int2* __restrict__ csr_edge,
                               const float* __restrict__ dinv, const float* __restrict__ b,
                               uint4* __restrict__ out4, const int* __restrict__ batch,
                               float* __restrict__ pooled, int N) {
    __shared__ int2 smeta[4][64];  // 2 KB, one strip per wave
    int wave = threadIdx.x >> 6;
    int lane = threadIdx.x & 63;
    int i = blockIdx.x * 4 + wave;
    if (i >= N) return;
    int q = lane >> 4;
    int l16 = lane & 15;

    int lo = ptr[i], hi = ptr[i + 1];
    int deg = hi - lo;

    float a0 = 0.f, a1 = 0.f, a2 = 0.f, a3 = 0.f, a4 = 0.f, a5 = 0.f, a6 = 0.f, a7 = 0.f;

    for (int base = 0; base < deg; base += 64) {
        int cnt = min(64, deg - base);
        if (lane < cnt) smeta[wave][lane] = csr_edge[lo + base + lane];
        // wave-private strip: same-wave ds ordering (compiler lgkmcnt) suffices, no barrier
        int jj = q;
        for (; jj + 4 < cnt; jj += 8) {
            int2 e0 = smeta[wave][jj];      // 16 lanes same addr -> LDS broadcast
            int2 e1 = smeta[wave][jj + 4];
            float c0 = __int_as_float(e0.y);
            float c1 = __int_as_float(e1.y);
            uint4 v0 = h4[(size_t)e0.x * 16 + l16];
            uint4 v1 = h4[(size_t)e1.x * 16 + l16];
            a0 += bf2f(v0.x & 0xffffu) * c0; a1 += bf2f(v0.x >> 16) * c0;
            a2 += bf2f(v0.y & 0xffffu) * c0; a3 += bf2f(v0.y >> 16) * c0;
            a4 += bf2f(v0.z & 0xffffu) * c0; a5 += bf2f(v0.z >> 16) * c0;
            a6 += bf2f(v0.w & 0xffffu) * c0; a7 += bf2f(v0.w >> 16) * c0;
            a0 += bf2f(v1.x & 0xffffu) * c1; a1 += bf2f(v1.x >> 16) * c1;
            a2 += bf2f(v1.y & 0xffffu) * c1; a3 += bf2f(v1.y >> 16) * c1;
            a4 += bf2f(v1.z & 0xffffu) * c1; a5 += bf2f(v1.z >> 16) * c1;
            a6 += bf2f(v1.w & 0xffffu) * c1; a7 += bf2f(v1.w >> 16) * c1;
        }
        if (jj < cnt) {
            int2 e0 = smeta[wave][jj];
            float c0 = __int_as_float(e0.y);
            uint4 v0 = h4[(size_t)e0.x * 16 + l16];
            a0 += bf2f(v0.x & 0xffffu) * c0; a1 += bf2f(v0.x >> 16) * c0;
            a2 += bf2f(v0.y & 0xffffu) * c0; a3 += bf2f(v0.y >> 16) * c0;
            a4 += bf2f(v0.z & 0xffffu) * c0; a5 += bf2f(v0.z >> 16) * c0;
            a6 += bf2f(v0.w & 0xffffu) * c0; a7 += bf2f(v0.w >> 16) * c0;
        }
    }
    // reduce the 4 quarters (same l16 -> same features); convergent here -> shfl defined
    a0 += __shfl_xor(a0, 16); a0 += __shfl_xor(a0, 32);
    a1 += __shfl_xor(a1, 16); a1 += __shfl_xor(a1, 32);
    a2 += __shfl_xor(a2, 16); a2 += __shfl_xor(a2, 32);
    a3 += __shfl_xor(a3, 16); a3 += __shfl_xor(a3, 32);
    a4 += __shfl_xor(a4, 16); a4 += __shfl_xor(a4, 32);
    a5 += __shfl_xor(a5, 16); a5 += __shfl_xor(a5, 32);
    a6 += __shfl_xor(a6, 16); a6 += __shfl_xor(a6, 32);
    a7 += __shfl_xor(a7, 16); a7 += __shfl_xor(a7, 32);

    float di = dinv[i];
    uint4 sv = h4[(size_t)i * 16 + l16];
    float4 bv0 = ((const float4*)b)[l16 * 2];
    float4 bv1 = ((const float4*)b)[l16 * 2 + 1];
    float dd = di * di;
    float v0 = a0 + bf2f(sv.x & 0xffffu) * dd + bv0.x;
    float v1 = a1 + bf2f(sv.x >> 16) * dd + bv0.y;
    float v2 = a2 + bf2f(sv.y & 0xffffu) * dd + bv0.z;
    float v3 = a3 + bf2f(sv.y >> 16) * dd + bv0.w;
    float v4 = a4 + bf2f(sv.z & 0xffffu) * dd + bv1.x;
    float v5 = a5 + bf2f(sv.z >> 16) * dd + bv1.y;
    float v6 = a6 + bf2f(sv.w & 0xffffu) * dd + bv1.z;
    float v7 = a7 + bf2f(sv.w >> 16) * dd + bv1.w;
    v0 = (v0 >= 0.f) ? v0 : NEG * v0;
    v1 = (v1 >= 0.f) ? v1 : NEG * v1;
    v2 = (v2 >= 0.f) ? v2 : NEG * v2;
    v3 = (v3 >= 0.f) ? v3 : NEG * v3;
    v4 = (v4 >= 0.f) ? v4 : NEG * v4;
    v5 = (v5 >= 0.f) ? v5 : NEG * v5;
    v6 = (v6 >= 0.f) ? v6 : NEG * v6;
    v7 = (v7 >= 0.f) ? v7 : NEG * v7;
    if (q == 0) {
        if (POOL) {
            int g = batch[i];
            float* p = pooled + g * D + l16 * 8;
            atomicAdd(p + 0, v0); atomicAdd(p + 1, v1);
            atomicAdd(p + 2, v2); atomicAdd(p + 3, v3);
            atomicAdd(p + 4, v4); atomicAdd(p + 5, v5);
            atomicAdd(p + 6, v6); atomicAdd(p + 7, v7);
        } else {
            uint4 pv;
            pv.x = (unsigned int)f2bf(v0) | ((unsigned int)f2bf(v1) << 16);
            pv.y = (unsigned int)f2bf(v2) | ((unsigned int)f2bf(v3) << 16);
            pv.z = (unsigned int)f2bf(v4) | ((unsigned int)f2bf(v5) << 16);
            pv.w = (unsigned int)f2bf(v6) | ((unsigned int)f2bf(v7) << 16);
            out4[(size_t)i * 16 + l16] = pv;
        }
    }
}

// ---------------- final linear: out[g,c] = (sum[g]/cnt[g]) . Wl[:,c] + bl[c] ----------------
__global__ void final_kernel(const float* __restrict__ pooled, const int* __restrict__ batch,
                             const float* __restrict__ Wl, const float* __restrict__ bl,
                             float* __restrict__ out, int N) {
    int t = blockIdx.x * blockDim.x + threadIdx.x;
    if (t >= NG * NC) return;
    int g = t >> 4, c = t & 15;
    int l = 0, h = N;
    while (l < h) { int m = (l + h) >> 1; if (batch[m] < g) l = m + 1; else h = m; }
    int lo = l;
    h = N;
    while (l < h) { int m = (l + h) >> 1; if (batch[m] < g + 1) l = m + 1; else h = m; }
    int cnt = l - lo;
    float inv = 1.0f / (float)(cnt > 0 ? cnt : 1);
    float dot = 0.f;
    for (int k = 0; k < D; k++) dot += pooled[g * D + k] * Wl[k * NC + c];
    out[t] = dot * inv + bl[c];
}

extern "C" void kernel_launch(void* const* d_in, const int* in_sizes, int n_in,
                              void* d_out, int out_size, void* d_ws, size_t ws_size,
                              hipStream_t stream) {
    const float* x = (const float*)d_in[0];
    const int* ei = (const int*)d_in[1];
    const int* batch = (const int*)d_in[2];
    const float* W1 = (const float*)d_in[3];
    const float* b1 = (const float*)d_in[4];
    const float* W2 = (const float*)d_in[5];
    const float* b2 = (const float*)d_in[6];
    const float* Wlin = (const float*)d_in[7];
    const float* bl = (const float*)d_in[8];
    float* out = (float*)d_out;

    int N = in_sizes[0] / D;
    int E = in_sizes[1] / 2;
    const int* src = ei;
    const int* dst = ei + E;

    // workspace layout (float units). 128x128 bf16 array = 16384 shorts = 8192 floats.
    float* ws = (float*)d_ws;
    size_t o = 0;
    unsigned int* bufA = (unsigned int*)(ws + o); o += (size_t)N * 64;  // 12.8 MB
    unsigned int* bufB = (unsigned int*)(ws + o); o += (size_t)N * 64;  // 12.8 MB
    int* deg = (int*)(ws + o);      o += N;       // zeroed by memset below
    int* fill = (int*)(ws + o);     o += N;       // zeroed inside finalize_ptr
    float* dinv = ws + o;           o += N;
    int* scan1 = (int*)(ws + o);    o += N;
    int* blocksum = (int*)(ws + o); o += 256;
    int* csr_ptr = (int*)(ws + o);  o += (N + 4);
    int2* csr_edge = (int2*)(ws + o); o += (size_t)2 * E;
    float* pooled = ws + o;         o += NG * D;
    unsigned short* Wf1 = (unsigned short*)(ws + o); o += 8192;  // fragment-order bf16 image
    unsigned short* Wf2 = (unsigned short*)(ws + o); o += 8192;

    hipMemsetAsync(deg, 0, (size_t)N * sizeof(int), stream);

    int tb = 256;
    int nscan = (N + 255) / 256;
    prep_misc_kernel<<<48 + (E + 255) / 256, 256, 0, stream>>>(W1, Wf1, W2, Wf2, pooled,
                                                               dst, deg, E);
    scan_block_kernel<<<nscan, 256, 0, stream>>>(deg, scan1, blocksum, dinv, N);
    finalize_ptr_kernel<<<nscan, 256, 0, stream>>>(deg, scan1, blocksum, csr_ptr, fill,
                                                   nscan, N, E);
    scatter_kernel<<<(E + tb - 1) / tb, tb, 0, stream>>>(src, dst, csr_ptr, fill, dinv,
                                                         csr_edge, E);

    int gblocks = (N + 63) / 64;
    int cblocks = (N + 3) / 4;
    // layer 1
    gemm_mfma_kernel<true><<<gblocks, 256, 0, stream>>>(x, (const uint4*)Wf1,
                                                        (unsigned int*)bufA, N);
    combine_kernel<false><<<cblocks, 256, 0, stream>>>((const uint4*)bufA, csr_ptr, csr_edge,
                                                       dinv, b1, (uint4*)bufB, batch, pooled, N);
    // layer 2
    gemm_mfma_kernel<false><<<gblocks, 256, 0, stream>>>(bufB, (const uint4*)Wf2,
                                                         (unsigned int*)bufA, N);
    combine_kernel<true><<<cblocks, 256, 0, stream>>>((const uint4*)bufA, csr_ptr, csr_edge,
                                                      dinv, b2, (uint4*)bufB, batch, pooled, N);
    // classifier (mean-pool already accumulated by combine<true>)
    final_kernel<<<(NG * NC + tb - 1) / tb, tb, 0, stream>>>(pooled, batch, Wlin, bl, out, N);
}

// Round 13
// 250.908 us; speedup vs baseline: 3.3036x; 3.3036x over previous
//
#include <hip/hip_runtime.h>

#define D 128
#define NG 64
#define NC 16
#define NEG 0.1f

typedef __attribute__((ext_vector_type(8))) short bf16x8;
typedef __attribute__((ext_vector_type(4))) float f32x4;

// ---------- bf16 <-> fp32 helpers (bf16 stored as ushort, packed pairs in uint) ----------
__device__ __forceinline__ float bf2f(unsigned int u16) {
    union { unsigned int i; float f; } c;
    c.i = u16 << 16;
    return c.f;
}
__device__ __forceinline__ unsigned short f2bf(float f) {
    union { float f; unsigned int i; } c;
    c.f = f;
    unsigned int i = c.i;
    unsigned int r = (i + 0x7FFFu + ((i >> 16) & 1u)) >> 16;  // RNE
    return (unsigned short)r;
}

// ---------------- fused prep ----------------
// blocks 0..15: W1/W2 -> bf16 fragment-order image; 16..47: zero pooled; 48+: degree histogram.
// Fragment order: entry (((t*4+kc)*4+quad)*16+m) = 8 bf16 of W[k][n], k=kc*32+quad*8.., n=t*16+m.
__global__ void prep_misc_kernel(const float* __restrict__ W1, unsigned short* __restrict__ Wf1,
                                 const float* __restrict__ W2, unsigned short* __restrict__ Wf2,
                                 float* __restrict__ pooled,
                                 const int* __restrict__ dst, int* __restrict__ deg, int E) {
    int b = blockIdx.x;
    if (b < 16) {
        const float* W = (b < 8) ? W1 : W2;
        unsigned short* Wf = (b < 8) ? Wf1 : Wf2;
        int fid = (b & 7) * 256 + threadIdx.x;  // 0..2047 fragment entries
        int m = fid & 15;
        int quad = (fid >> 4) & 3;
        int kc = (fid >> 6) & 3;
        int t = fid >> 8;
        int n = t * 16 + m;
        int k0 = kc * 32 + quad * 8;
        unsigned short r[8];
#pragma unroll
        for (int j = 0; j < 8; j++) r[j] = f2bf(W[(k0 + j) * 128 + n]);
        uint4 v;
        v.x = (unsigned int)r[0] | ((unsigned int)r[1] << 16);
        v.y = (unsigned int)r[2] | ((unsigned int)r[3] << 16);
        v.z = (unsigned int)r[4] | ((unsigned int)r[5] << 16);
        v.w = (unsigned int)r[6] | ((unsigned int)r[7] << 16);
        ((uint4*)Wf)[fid] = v;
    } else if (b < 48) {
        pooled[(b - 16) * 256 + threadIdx.x] = 0.f;
    } else {
        int e = (b - 48) * 256 + threadIdx.x;
        if (e < E) atomicAdd(&deg[dst[e]], 1);
    }
}

// ---------------- scan stage 1 (+ dinv fold) ----------------
__global__ void scan_block_kernel(const int* __restrict__ deg, int* __restrict__ scan1,
                                  int* __restrict__ blocksum, float* __restrict__ dinv, int N) {
    __shared__ int sm[256];
    int tid = threadIdx.x;
    int i = blockIdx.x * 256 + tid;
    int v = (i < N) ? deg[i] : 0;
    if (i < N) dinv[i] = 1.0f / sqrtf((float)v + 1.0f);
    sm[tid] = v;
    __syncthreads();
    for (int off = 1; off < 256; off <<= 1) {
        int t = (tid >= off) ? sm[tid - off] : 0;
        __syncthreads();
        sm[tid] += t;
        __syncthreads();
    }
    if (i < N) scan1[i] = sm[tid];  // inclusive
    if (tid == 255) blocksum[blockIdx.x] = sm[255];
}

// ---------------- finalize: ptr = exclusive prefix; each block re-scans blocksum in LDS ----------
// (nscan <= 256 guaranteed: N <= 65536). Also zeroes fill[] ahead of scatter.
__global__ void finalize_ptr_kernel(const int* __restrict__ deg, const int* __restrict__ scan1,
                                    const int* __restrict__ blocksum, int* __restrict__ ptr,
                                    int* __restrict__ fill, int nb, int N, int E) {
    __shared__ int sm[256];
    int tid = threadIdx.x;
    int v = (tid < nb) ? blocksum[tid] : 0;
    sm[tid] = v;
    __syncthreads();
    for (int off = 1; off < 256; off <<= 1) {
        int t = (tid >= off) ? sm[tid - off] : 0;
        __syncthreads();
        sm[tid] += t;
        __syncthreads();
    }
    int blockoff = (blockIdx.x > 0) ? sm[blockIdx.x - 1] : 0;  // exclusive prefix for this block
    int i = blockIdx.x * 256 + tid;
    if (i < N) {
        ptr[i] = scan1[i] - deg[i] + blockoff;
        fill[i] = 0;
        if (i == N - 1) ptr[N] = E;
    }
}

// ---------------- scatter edges into CSR by dst; packed (src, coef) int2 ----------------
__global__ void scatter_kernel(const int* __restrict__ src, const int* __restrict__ dst,
                               const int* __restrict__ ptr, int* __restrict__ fill,
                               const float* __restrict__ dinv,
                               int2* __restrict__ csr_edge, int E) {
    int e = blockIdx.x * blockDim.x + threadIdx.x;
    if (e < E) {
        int d = dst[e];
        int s = src[e];
        int pos = ptr[d] + atomicAdd(&fill[d], 1);
        float coef = dinv[s] * dinv[d];
        csr_edge[pos] = make_int2(s, __float_as_int(coef));
    }
}

// ---------------- MFMA GEMM: C[N,128](packed bf16) = A[N,128] @ W ----------------
// 256 thr (4 waves), 64 rows/block. A fragments straight from global (read once);
// W (fragment-order bf16 image, 32 KB) staged to LDS 1:1, read as contiguous 1KB/wave.
template <bool AF32>
__global__ __launch_bounds__(256) void gemm_mfma_kernel(const void* __restrict__ Ap,
                                                        const uint4* __restrict__ Wf,
                                                        unsigned int* __restrict__ C, int N) {
    __shared__ uint4 Ws[2048];  // 32 KB, fragment-order image
    int tid = threadIdx.x;
    int w = tid >> 6, lane = tid & 63;
    int quad = lane >> 4, m = lane & 15;
    int rowstart = blockIdx.x * 64;

    // stage W image (contiguous copy)
#pragma unroll
    for (int i = 0; i < 8; i++) Ws[tid + 256 * i] = Wf[tid + 256 * i];

    // A fragments from global: row 16w+m, k = kc*32 + quad*8 + j
    int arow = rowstart + 16 * w + m;
    bool valid = arow < N;
    bf16x8 af[4];
    if (AF32) {
        const float* Ag = (const float*)Ap;
#pragma unroll
        for (int kc = 0; kc < 4; kc++) {
            float4 f0 = make_float4(0.f, 0.f, 0.f, 0.f), f1 = f0;
            if (valid) {
                const float4* p = (const float4*)(Ag + (size_t)arow * 128 + kc * 32 + quad * 8);
                f0 = p[0];
                f1 = p[1];
            }
            bf16x8 a;
            a[0] = (short)f2bf(f0.x); a[1] = (short)f2bf(f0.y);
            a[2] = (short)f2bf(f0.z); a[3] = (short)f2bf(f0.w);
            a[4] = (short)f2bf(f1.x); a[5] = (short)f2bf(f1.y);
            a[6] = (short)f2bf(f1.z); a[7] = (short)f2bf(f1.w);
            af[kc] = a;
        }
    } else {
        const unsigned short* Ag = (const unsigned short*)Ap;
#pragma unroll
        for (int kc = 0; kc < 4; kc++) {
            bf16x8 a;
#pragma unroll
            for (int j = 0; j < 8; j++) a[j] = 0;
            if (valid) a = *(const bf16x8*)(Ag + (size_t)arow * 128 + kc * 32 + quad * 8);
            af[kc] = a;
        }
    }
    __syncthreads();

    f32x4 acc[8];
#pragma unroll
    for (int t = 0; t < 8; t++) acc[t] = (f32x4){0.f, 0.f, 0.f, 0.f};

#pragma unroll
    for (int t = 0; t < 8; t++) {
#pragma unroll
        for (int kc = 0; kc < 4; kc++) {
            bf16x8 bh = *(const bf16x8*)&Ws[(((t * 4 + kc) * 4 + quad) * 16 + m)];
            acc[t] = __builtin_amdgcn_mfma_f32_16x16x32_bf16(af[kc], bh, acc[t], 0, 0, 0);
        }
    }

    // epilogue: C[row = 16w + quad*4 + r][col = t*16 + m]; pack pairs across m via shfl_xor(1)
    // (shfl in CONVERGENT code: all 64 lanes active -> defined)
#pragma unroll
    for (int t = 0; t < 8; t++) {
#pragma unroll
        for (int r = 0; r < 4; r++) {
            int row = rowstart + 16 * w + quad * 4 + r;
            unsigned int us = f2bf(acc[t][r]);
            unsigned int other = (unsigned int)__shfl_xor((int)us, 1);
            if (((m & 1) == 0) && row < N)
                C[(size_t)row * 64 + t * 8 + (m >> 1)] = us | (other << 16);
        }
    }
}

// ---------------- gather + self-loop + bias + leaky_relu ----------------
// one wave per node; 16 lanes/row (uint4 = 8 feats), 4 rows in flight, 2x unroll.
// Edge meta: one coalesced 64-edge load per wave into a WAVE-PRIVATE LDS strip, then
// ds_read broadcast (well-defined under divergence, unlike __shfl).
__global__ void combine_kernel(const uint4* __restrict__ h4, const int* __restrict__ ptr,
                               const int2* __restrict__ csr_edge,
                               const float* __restrict__ dinv, const float* __restrict__ b,
                               uint4* __restrict__ out4, int N) {
    __shared__ int2 smeta[4][64];  // 2 KB, one strip per wave
    int wave = threadIdx.x >> 6;
    int lane = threadIdx.x & 63;
    int i = blockIdx.x * 4 + wave;
    if (i >= N) return;
    int q = lane >> 4;
    int l16 = lane & 15;

    int lo = ptr[i], hi = ptr[i + 1];
    int deg = hi - lo;

    float a0 = 0.f, a1 = 0.f, a2 = 0.f, a3 = 0.f, a4 = 0.f, a5 = 0.f, a6 = 0.f, a7 = 0.f;

    for (int base = 0; base < deg; base += 64) {
        int cnt = min(64, deg - base);
        if (lane < cnt) smeta[wave][lane] = csr_edge[lo + base + lane];
        // wave-private strip: same-wave ds ordering (compiler lgkmcnt) suffices, no barrier
        int jj = q;
        for (; jj + 4 < cnt; jj += 8) {
            int2 e0 = smeta[wave][jj];      // 16 lanes same addr -> LDS broadcast
            int2 e1 = smeta[wave][jj + 4];
            float c0 = __int_as_float(e0.y);
            float c1 = __int_as_float(e1.y);
            uint4 v0 = h4[(size_t)e0.x * 16 + l16];
            uint4 v1 = h4[(size_t)e1.x * 16 + l16];
            a0 += bf2f(v0.x & 0xffffu) * c0; a1 += bf2f(v0.x >> 16) * c0;
            a2 += bf2f(v0.y & 0xffffu) * c0; a3 += bf2f(v0.y >> 16) * c0;
            a4 += bf2f(v0.z & 0xffffu) * c0; a5 += bf2f(v0.z >> 16) * c0;
            a6 += bf2f(v0.w & 0xffffu) * c0; a7 += bf2f(v0.w >> 16) * c0;
            a0 += bf2f(v1.x & 0xffffu) * c1; a1 += bf2f(v1.x >> 16) * c1;
            a2 += bf2f(v1.y & 0xffffu) * c1; a3 += bf2f(v1.y >> 16) * c1;
            a4 += bf2f(v1.z & 0xffffu) * c1; a5 += bf2f(v1.z >> 16) * c1;
            a6 += bf2f(v1.w & 0xffffu) * c1; a7 += bf2f(v1.w >> 16) * c1;
        }
        if (jj < cnt) {
            int2 e0 = smeta[wave][jj];
            float c0 = __int_as_float(e0.y);
            uint4 v0 = h4[(size_t)e0.x * 16 + l16];
            a0 += bf2f(v0.x & 0xffffu) * c0; a1 += bf2f(v0.x >> 16) * c0;
            a2 += bf2f(v0.y & 0xffffu) * c0; a3 += bf2f(v0.y >> 16) * c0;
            a4 += bf2f(v0.z & 0xffffu) * c0; a5 += bf2f(v0.z >> 16) * c0;
            a6 += bf2f(v0.w & 0xffffu) * c0; a7 += bf2f(v0.w >> 16) * c0;
        }
    }
    // reduce the 4 quarters (same l16 -> same features); convergent here -> shfl defined
    a0 += __shfl_xor(a0, 16); a0 += __shfl_xor(a0, 32);
    a1 += __shfl_xor(a1, 16); a1 += __shfl_xor(a1, 32);
    a2 += __shfl_xor(a2, 16); a2 += __shfl_xor(a2, 32);
    a3 += __shfl_xor(a3, 16); a3 += __shfl_xor(a3, 32);
    a4 += __shfl_xor(a4, 16); a4 += __shfl_xor(a4, 32);
    a5 += __shfl_xor(a5, 16); a5 += __shfl_xor(a5, 32);
    a6 += __shfl_xor(a6, 16); a6 += __shfl_xor(a6, 32);
    a7 += __shfl_xor(a7, 16); a7 += __shfl_xor(a7, 32);

    float di = dinv[i];
    uint4 sv = h4[(size_t)i * 16 + l16];
    float4 bv0 = ((const float4*)b)[l16 * 2];
    float4 bv1 = ((const float4*)b)[l16 * 2 + 1];
    float dd = di * di;
    float v0 = a0 + bf2f(sv.x & 0xffffu) * dd + bv0.x;
    float v1 = a1 + bf2f(sv.x >> 16) * dd + bv0.y;
    float v2 = a2 + bf2f(sv.y & 0xffffu) * dd + bv0.z;
    float v3 = a3 + bf2f(sv.y >> 16) * dd + bv0.w;
    float v4 = a4 + bf2f(sv.z & 0xffffu) * dd + bv1.x;
    float v5 = a5 + bf2f(sv.z >> 16) * dd + bv1.y;
    float v6 = a6 + bf2f(sv.w & 0xffffu) * dd + bv1.z;
    float v7 = a7 + bf2f(sv.w >> 16) * dd + bv1.w;
    v0 = (v0 >= 0.f) ? v0 : NEG * v0;
    v1 = (v1 >= 0.f) ? v1 : NEG * v1;
    v2 = (v2 >= 0.f) ? v2 : NEG * v2;
    v3 = (v3 >= 0.f) ? v3 : NEG * v3;
    v4 = (v4 >= 0.f) ? v4 : NEG * v4;
    v5 = (v5 >= 0.f) ? v5 : NEG * v5;
    v6 = (v6 >= 0.f) ? v6 : NEG * v6;
    v7 = (v7 >= 0.f) ? v7 : NEG * v7;
    if (q == 0) {
        uint4 pv;
        pv.x = (unsigned int)f2bf(v0) | ((unsigned int)f2bf(v1) << 16);
        pv.y = (unsigned int)f2bf(v2) | ((unsigned int)f2bf(v3) << 16);
        pv.z = (unsigned int)f2bf(v4) | ((unsigned int)f2bf(v5) << 16);
        pv.w = (unsigned int)f2bf(v6) | ((unsigned int)f2bf(v7) << 16);
        out4[(size_t)i * 16 + l16] = pv;
    }
}

// ---------------- pool: node-parallel chunked accumulate (batch sorted) ----------------
#define PROWS 128
__global__ void pool_accum_kernel(const unsigned int* __restrict__ a2,
                                  const int* __restrict__ batch,
                                  float* __restrict__ pooled, int N) {
    int wave = threadIdx.x >> 6;
    int lane = threadIdx.x & 63;
    int start = blockIdx.x * PROWS;
    int end = start + PROWS;
    if (end > N) end = N;
    float s0 = 0.f, s1 = 0.f;
    int curg = -1;
    for (int r = start + wave; r < end; r += 4) {
        int g = batch[r];  // wave-uniform (sorted batch)
        if (g != curg) {
            if (curg >= 0) {
                atomicAdd(&pooled[curg * D + 2 * lane], s0);
                atomicAdd(&pooled[curg * D + 2 * lane + 1], s1);
            }
            curg = g;
            s0 = 0.f;
            s1 = 0.f;
        }
        unsigned int v = a2[(size_t)r * 64 + lane];
        s0 += bf2f(v & 0xffffu);
        s1 += bf2f(v >> 16);
    }
    if (curg >= 0) {
        atomicAdd(&pooled[curg * D + 2 * lane], s0);
        atomicAdd(&pooled[curg * D + 2 * lane + 1], s1);
    }
}

// ---------------- final linear: out[g,c] = (sum[g]/cnt[g]) . Wl[:,c] + bl[c] ----------------
__global__ void final_kernel(const float* __restrict__ pooled, const int* __restrict__ batch,
                             const float* __restrict__ Wl, const float* __restrict__ bl,
                             float* __restrict__ out, int N) {
    int t = blockIdx.x * blockDim.x + threadIdx.x;
    if (t >= NG * NC) return;
    int g = t >> 4, c = t & 15;
    int l = 0, h = N;
    while (l < h) { int m = (l + h) >> 1; if (batch[m] < g) l = m + 1; else h = m; }
    int lo = l;
    h = N;
    while (l < h) { int m = (l + h) >> 1; if (batch[m] < g + 1) l = m + 1; else h = m; }
    int cnt = l - lo;
    float inv = 1.0f / (float)(cnt > 0 ? cnt : 1);
    float dot = 0.f;
    for (int k = 0; k < D; k++) dot += pooled[g * D + k] * Wl[k * NC + c];
    out[t] = dot * inv + bl[c];
}

extern "C" void kernel_launch(void* const* d_in, const int* in_sizes, int n_in,
                              void* d_out, int out_size, void* d_ws, size_t ws_size,
                              hipStream_t stream) {
    const float* x = (const float*)d_in[0];
    const int* ei = (const int*)d_in[1];
    const int* batch = (const int*)d_in[2];
    const float* W1 = (const float*)d_in[3];
    const float* b1 = (const float*)d_in[4];
    const float* W2 = (const float*)d_in[5];
    const float* b2 = (const float*)d_in[6];
    const float* Wlin = (const float*)d_in[7];
    const float* bl = (const float*)d_in[8];
    float* out = (float*)d_out;

    int N = in_sizes[0] / D;
    int E = in_sizes[1] / 2;
    const int* src = ei;
    const int* dst = ei + E;

    // workspace layout (float units). 128x128 bf16 array = 16384 shorts = 8192 floats.
    float* ws = (float*)d_ws;
    size_t o = 0;
    unsigned int* bufA = (unsigned int*)(ws + o); o += (size_t)N * 64;  // 12.8 MB
    unsigned int* bufB = (unsigned int*)(ws + o); o += (size_t)N * 64;  // 12.8 MB
    int* deg = (int*)(ws + o);      o += N;       // zeroed by memset below
    int* fill = (int*)(ws + o);     o += N;       // zeroed inside finalize_ptr
    float* dinv = ws + o;           o += N;
    int* scan1 = (int*)(ws + o);    o += N;
    int* blocksum = (int*)(ws + o); o += 256;
    int* csr_ptr = (int*)(ws + o);  o += (N + 4);
    int2* csr_edge = (int2*)(ws + o); o += (size_t)2 * E;
    float* pooled = ws + o;         o += NG * D;
    unsigned short* Wf1 = (unsigned short*)(ws + o); o += 8192;  // fragment-order bf16 image
    unsigned short* Wf2 = (unsigned short*)(ws + o); o += 8192;

    hipMemsetAsync(deg, 0, (size_t)N * sizeof(int), stream);

    int tb = 256;
    int nscan = (N + 255) / 256;
    prep_misc_kernel<<<48 + (E + 255) / 256, 256, 0, stream>>>(W1, Wf1, W2, Wf2, pooled,
                                                               dst, deg, E);
    scan_block_kernel<<<nscan, 256, 0, stream>>>(deg, scan1, blocksum, dinv, N);
    finalize_ptr_kernel<<<nscan, 256, 0, stream>>>(deg, scan1, blocksum, csr_ptr, fill,
                                                   nscan, N, E);
    scatter_kernel<<<(E + tb - 1) / tb, tb, 0, stream>>>(src, dst, csr_ptr, fill, dinv,
                                                         csr_edge, E);

    int gblocks = (N + 63) / 64;
    int cblocks = (N + 3) / 4;
    // layer 1
    gemm_mfma_kernel<true><<<gblocks, 256, 0, stream>>>(x, (const uint4*)Wf1,
                                                        (unsigned int*)bufA, N);
    combine_kernel<<<cblocks, 256, 0, stream>>>((const uint4*)bufA, csr_ptr, csr_edge,
                                                dinv, b1, (uint4*)bufB, N);
    // layer 2
    gemm_mfma_kernel<false><<<gblocks, 256, 0, stream>>>(bufB, (const uint4*)Wf2,
                                                         (unsigned int*)bufA, N);
    combine_kernel<<<cblocks, 256, 0, stream>>>((const uint4*)bufA, csr_ptr, csr_edge,
                                                dinv, b2, (uint4*)bufB, N);
    // pool + classifier
    pool_accum_kernel<<<(N + PROWS - 1) / PROWS, 256, 0, stream>>>(bufB, batch, pooled, N);
    final_kernel<<<(NG * NC + tb - 1) / tb, tb, 0, stream>>>(pooled, batch, Wlin, bl, out, N);
}